// Round 1
// baseline (549.273 us; speedup 1.0000x reference)
//
#include <hip/hip_runtime.h>

typedef __bf16 bf16x8 __attribute__((ext_vector_type(8)));
typedef float f32x4 __attribute__((ext_vector_type(4)));
typedef unsigned short u16;
typedef unsigned int u32;
typedef u16 u16x8 __attribute__((ext_vector_type(8)));

#define DEVFN static __device__ __forceinline__

constexpr int T = 4096, H = 1024, I = 2048, E = 8;
constexpr int NSLOT = T * 2;        // every token contributes exactly 2 slots
constexpr int BM = 128, BK = 32;
constexpr int MAX_TILES = 72;       // ceil(8192/128) + (E-1) = 71 max

DEVFN u16 f2bf(float f) {
  u32 u = __builtin_bit_cast(u32, f);
  u32 r = (u + 0x7FFFu + ((u >> 16) & 1u)) >> 16;  // RNE
  return (u16)r;
}

DEVFN void glds16(const void* g, void* l) {
  __builtin_amdgcn_global_load_lds(
      (const __attribute__((address_space(1))) void*)g,
      (__attribute__((address_space(3))) void*)l, 16, 0, 0);
}

// ---------------- fp32 -> bf16 bulk convert (8 elems/thread/iter) ----------------
__global__ void cvt_f32_bf16(const float* __restrict__ s, u16* __restrict__ d, int n8) {
  int i = blockIdx.x * blockDim.x + threadIdx.x;
  int stride = gridDim.x * blockDim.x;
  for (; i < n8; i += stride) {
    const float4* s4 = (const float4*)s + (size_t)i * 2;
    float4 x0 = s4[0], x1 = s4[1];
    u16x8 o;
    o[0] = f2bf(x0.x); o[1] = f2bf(x0.y); o[2] = f2bf(x0.z); o[3] = f2bf(x0.w);
    o[4] = f2bf(x1.x); o[5] = f2bf(x1.y); o[6] = f2bf(x1.z); o[7] = f2bf(x1.w);
    *((u16x8*)d + i) = o;
  }
}

// ---------------- router ----------------
DEVFN void top2(const float* __restrict__ logits, int t, int& i0, int& i1, float& v0, float& v1) {
  float l[E];
#pragma unroll
  for (int i = 0; i < E; i++) l[i] = logits[t * E + i];
  i0 = 0; v0 = l[0];
#pragma unroll
  for (int i = 1; i < E; i++) if (l[i] > v0) { v0 = l[i]; i0 = i; }
  i1 = -1; v1 = -1e30f;
#pragma unroll
  for (int i = 0; i < E; i++) if (i != i0 && l[i] > v1) { v1 = l[i]; i1 = i; }
}

__global__ void router_count(const float* __restrict__ logits, int* __restrict__ counts) {
  int t = blockIdx.x * blockDim.x + threadIdx.x;
  if (t >= T) return;
  int i0, i1; float v0, v1;
  top2(logits, t, i0, i1, v0, v1);
  atomicAdd(&counts[i0], 1);
  atomicAdd(&counts[i1], 1);
}

__global__ void build_tiles(const int* __restrict__ counts, int* __restrict__ offsets,
                            int* __restrict__ ntiles, int* __restrict__ tile_e,
                            int* __restrict__ tile_r0) {
  if (threadIdx.x != 0 || blockIdx.x != 0) return;
  int s = 0, nt = 0;
  for (int e = 0; e < E; e++) {
    offsets[e] = s;
    for (int r = 0; r < counts[e]; r += BM) { tile_e[nt] = e; tile_r0[nt] = r; nt++; }
    s += counts[e];
  }
  offsets[E] = s;
  ntiles[0] = nt;
}

__global__ void router_scatter(const float* __restrict__ logits, const int* __restrict__ offsets,
                               int* __restrict__ cursor, int* __restrict__ slot_tok,
                               float* __restrict__ slot_w) {
  int t = blockIdx.x * blockDim.x + threadIdx.x;
  if (t >= T) return;
  int i0, i1; float v0, v1;
  top2(logits, t, i0, i1, v0, v1);
  // renormalized top-2 softmax: denominator cancels
  float ee = __expf(v1 - v0);
  float w0 = 1.f / (1.f + ee);
  float w1 = 1.f - w0;
  int p0 = offsets[i0] + atomicAdd(&cursor[i0], 1);
  slot_tok[p0] = t; slot_w[p0] = w0;
  int p1 = offsets[i1] + atomicAdd(&cursor[i1], 1);
  slot_tok[p1] = t; slot_w[p1] = w1;
}

// ---------------- GEMM1: h = silu(x@w1^T) * (x@w3^T), gathered rows ----------------
// block: 128 rows x 64 cols (of gate AND up), 4 waves, each wave 64x32 per matrix
__global__ __launch_bounds__(256, 2) void gemm1(
    const u16* __restrict__ xb, const u16* __restrict__ w13b,
    const int* __restrict__ offsets, const int* __restrict__ ntiles,
    const int* __restrict__ tile_e, const int* __restrict__ tile_r0,
    const int* __restrict__ slot_tok, u16* __restrict__ hb) {
  int ti = blockIdx.x;
  if (ti >= ntiles[0]) return;
  int e = tile_e[ti], row0 = tile_r0[ti];
  int n0 = offsets[e], ne = offsets[e + 1] - n0;
  int j0 = blockIdx.y * 64;

  __shared__ u16 As[BM * BK];    // [128][32] bf16, 64B rows
  __shared__ u16 Bgs[64 * BK];
  __shared__ u16 Bus[64 * BK];

  int tid = threadIdx.x, w = tid >> 6, l = tid & 63;
  int lr = l & 15, lh = l >> 4;
  int wm = w >> 1, wn = w & 1;

  const char* xc = (const char*)xb;
  const char* wc = (const char*)w13b;

  // A staging: 512 chunks of 16B; chunk c = tid + i*256; row=c>>2, bytecol=(c&3)*16
  size_t aoff[2];
#pragma unroll
  for (int i = 0; i < 2; i++) {
    int c = tid + i * 256;
    int r = c >> 2;
    int rr = row0 + r; if (rr > ne - 1) rr = ne - 1;   // clamp tail rows
    int tok = slot_tok[n0 + rr];
    aoff[i] = (size_t)tok * (H * 2) + (size_t)((c & 3) * 16);
  }
  // B staging: 256 chunks each for gate/up; chunk c = tid
  int jr = tid >> 2, bb = (tid & 3) * 16;
  size_t goff = ((size_t)e * (2 * I) + (j0 + jr)) * (H * 2) + bb;
  size_t uoff = ((size_t)e * (2 * I) + I + (j0 + jr)) * (H * 2) + bb;

  f32x4 accg[4][2] = {};
  f32x4 accu[4][2] = {};

  char* AsB = (char*)As; char* BgB = (char*)Bgs; char* BuB = (char*)Bus;

  for (int k0 = 0; k0 < H; k0 += BK) {
    __syncthreads();
    size_t kb = (size_t)(k0 * 2);
    glds16(xc + aoff[0] + kb, AsB + (w * 64) * 16);
    glds16(xc + aoff[1] + kb, AsB + (w * 64 + 256) * 16);
    glds16(wc + goff + kb, BgB + (w * 64) * 16);
    glds16(wc + uoff + kb, BuB + (w * 64) * 16);
    __syncthreads();

    bf16x8 a[4], bg[2], bu[2];
#pragma unroll
    for (int mi = 0; mi < 4; mi++)
      a[mi] = *(const bf16x8*)&As[(wm * 64 + mi * 16 + lr) * BK + lh * 8];
#pragma unroll
    for (int ni = 0; ni < 2; ni++) {
      bg[ni] = *(const bf16x8*)&Bgs[(wn * 32 + ni * 16 + lr) * BK + lh * 8];
      bu[ni] = *(const bf16x8*)&Bus[(wn * 32 + ni * 16 + lr) * BK + lh * 8];
    }
#pragma unroll
    for (int mi = 0; mi < 4; mi++)
#pragma unroll
      for (int ni = 0; ni < 2; ni++) {
        accg[mi][ni] = __builtin_amdgcn_mfma_f32_16x16x32_bf16(a[mi], bg[ni], accg[mi][ni], 0, 0, 0);
        accu[mi][ni] = __builtin_amdgcn_mfma_f32_16x16x32_bf16(a[mi], bu[ni], accu[mi][ni], 0, 0, 0);
      }
  }

  // epilogue: h = silu(g)*u, store bf16
#pragma unroll
  for (int mi = 0; mi < 4; mi++) {
    int Rb = row0 + wm * 64 + mi * 16 + lh * 4;
#pragma unroll
    for (int ni = 0; ni < 2; ni++) {
      int col = j0 + wn * 32 + ni * 16 + lr;
      f32x4 g = accg[mi][ni], u = accu[mi][ni];
#pragma unroll
      for (int r = 0; r < 4; r++) {
        int R = Rb + r;
        if (R < ne) {
          float gg = g[r];
          float hh = (gg / (1.f + __expf(-gg))) * u[r];
          hb[(size_t)(n0 + R) * I + col] = f2bf(hh);
        }
      }
    }
  }
}

// ---------------- GEMM2: y = h@w2^T, scaled atomic-scatter into out ----------------
__global__ __launch_bounds__(256, 2) void gemm2(
    const u16* __restrict__ hb, const u16* __restrict__ w2b,
    const int* __restrict__ offsets, const int* __restrict__ ntiles,
    const int* __restrict__ tile_e, const int* __restrict__ tile_r0,
    const int* __restrict__ slot_tok, const float* __restrict__ slot_w,
    float* __restrict__ out) {
  int ti = blockIdx.x;
  if (ti >= ntiles[0]) return;
  int e = tile_e[ti], row0 = tile_r0[ti];
  int n0 = offsets[e], ne = offsets[e + 1] - n0;
  int j0 = blockIdx.y * 128;

  __shared__ u16 As[BM * BK];
  __shared__ u16 Bs[BM * BK];

  int tid = threadIdx.x, w = tid >> 6, l = tid & 63;
  int lr = l & 15, lh = l >> 4;
  int wm = w >> 1, wn = w & 1;

  const char* hc = (const char*)hb;
  const char* wc = (const char*)w2b;

  size_t aoff[2], boff[2];
#pragma unroll
  for (int i = 0; i < 2; i++) {
    int c = tid + i * 256;
    int r = c >> 2;
    int rr = row0 + r; if (rr > ne - 1) rr = ne - 1;
    aoff[i] = (size_t)(n0 + rr) * (I * 2) + (size_t)((c & 3) * 16);
    boff[i] = ((size_t)e * H + j0 + r) * (I * 2) + (size_t)((c & 3) * 16);
  }

  f32x4 acc[4][4] = {};

  for (int k0 = 0; k0 < I; k0 += BK) {
    __syncthreads();
    size_t kb = (size_t)(k0 * 2);
    glds16(hc + aoff[0] + kb, (char*)As + (w * 64) * 16);
    glds16(hc + aoff[1] + kb, (char*)As + (w * 64 + 256) * 16);
    glds16(wc + boff[0] + kb, (char*)Bs + (w * 64) * 16);
    glds16(wc + boff[1] + kb, (char*)Bs + (w * 64 + 256) * 16);
    __syncthreads();

    bf16x8 a[4], b[4];
#pragma unroll
    for (int mi = 0; mi < 4; mi++)
      a[mi] = *(const bf16x8*)&As[(wm * 64 + mi * 16 + lr) * BK + lh * 8];
#pragma unroll
    for (int nj = 0; nj < 4; nj++)
      b[nj] = *(const bf16x8*)&Bs[(wn * 64 + nj * 16 + lr) * BK + lh * 8];
#pragma unroll
    for (int mi = 0; mi < 4; mi++)
#pragma unroll
      for (int nj = 0; nj < 4; nj++)
        acc[mi][nj] = __builtin_amdgcn_mfma_f32_16x16x32_bf16(a[mi], b[nj], acc[mi][nj], 0, 0, 0);
  }

#pragma unroll
  for (int mi = 0; mi < 4; mi++) {
    int Rb = row0 + wm * 64 + mi * 16 + lh * 4;
#pragma unroll
    for (int r = 0; r < 4; r++) {
      int R = Rb + r;
      if (R < ne) {
        int tok = slot_tok[n0 + R];
        float cw = slot_w[n0 + R];
        float* orow = out + (size_t)tok * H + j0 + wn * 64 + lr;
#pragma unroll
        for (int nj = 0; nj < 4; nj++)
          atomicAdd(&orow[nj * 16], acc[mi][nj][r] * cw);
      }
    }
  }
}

// ---------------- host ----------------
extern "C" void kernel_launch(void* const* d_in, const int* in_sizes, int n_in,
                              void* d_out, int out_size, void* d_ws, size_t ws_size,
                              hipStream_t stream) {
  const float* x      = (const float*)d_in[0];
  const float* logits = (const float*)d_in[1];
  const float* w13    = (const float*)d_in[2];
  const float* w2     = (const float*)d_in[3];
  float* out = (float*)d_out;

  char* ws = (char*)d_ws;
  size_t off = 0;
  auto alloc = [&](size_t b) { size_t p = off; off += (b + 255) & ~(size_t)255; return p; };
  int*   counts   = (int*)(ws + alloc(E * 4));
  int*   cursor   = (int*)(ws + alloc(E * 4));
  int*   offsets  = (int*)(ws + alloc((E + 1) * 4));
  int*   ntiles   = (int*)(ws + alloc(4));
  int*   tile_e   = (int*)(ws + alloc(MAX_TILES * 4));
  int*   tile_r0  = (int*)(ws + alloc(MAX_TILES * 4));
  int*   slot_tok = (int*)(ws + alloc(NSLOT * 4));
  float* slot_w   = (float*)(ws + alloc(NSLOT * 4));
  u16*   xb       = (u16*)(ws + alloc((size_t)T * H * 2));
  u16*   w13b     = (u16*)(ws + alloc((size_t)E * 2 * I * H * 2));
  u16*   w2b      = (u16*)(ws + alloc((size_t)E * H * I * 2));
  u16*   hb       = (u16*)(ws + alloc((size_t)NSLOT * I * 2));
  if (ws_size < off) return;  // ~143 MB needed; fail loudly (validation) rather than corrupt

  hipMemsetAsync(ws, 0, 512, stream);                            // counts + cursor
  hipMemsetAsync(d_out, 0, (size_t)T * H * sizeof(float), stream);

  cvt_f32_bf16<<<2048, 256, 0, stream>>>(x, xb, T * H / 8);
  cvt_f32_bf16<<<2048, 256, 0, stream>>>(w13, w13b, E * 2 * I * H / 8);
  cvt_f32_bf16<<<2048, 256, 0, stream>>>(w2, w2b, E * H * I / 8);

  router_count<<<T / 256, 256, 0, stream>>>(logits, counts);
  build_tiles<<<1, 64, 0, stream>>>(counts, offsets, ntiles, tile_e, tile_r0);
  router_scatter<<<T / 256, 256, 0, stream>>>(logits, offsets, cursor, slot_tok, slot_w);

  gemm1<<<dim3(MAX_TILES, I / 64, 1), 256, 0, stream>>>(
      xb, w13b, offsets, ntiles, tile_e, tile_r0, slot_tok, hb);
  gemm2<<<dim3(MAX_TILES, H / 128, 1), 256, 0, stream>>>(
      hb, w2b, offsets, ntiles, tile_e, tile_r0, slot_tok, slot_w, out);
}

// Round 2
// 508.087 us; speedup vs baseline: 1.0811x; 1.0811x over previous
//
#include <hip/hip_runtime.h>

typedef __bf16 bf16x8 __attribute__((ext_vector_type(8)));
typedef float f32x4 __attribute__((ext_vector_type(4)));
typedef unsigned short u16;
typedef unsigned int u32;
typedef u16 u16x8 __attribute__((ext_vector_type(8)));

#define DEVFN static __device__ __forceinline__

constexpr int T = 4096, H = 1024, I = 2048, E = 8;
constexpr int NSLOT = T * 2;
constexpr int BM = 128, BK = 64;     // K elems per step; row = 128 bytes
constexpr int BKB = BK * 2;          // bytes per LDS row
constexpr int MAX_TILES = 72;

DEVFN u16 f2bf(float f) {
  u32 u = __builtin_bit_cast(u32, f);
  u32 r = (u + 0x7FFFu + ((u >> 16) & 1u)) >> 16;  // RNE
  return (u16)r;
}

DEVFN void glds16(const void* g, void* l) {
  __builtin_amdgcn_global_load_lds(
      (const __attribute__((address_space(1))) void*)g,
      (__attribute__((address_space(3))) void*)l, 16, 0, 0);
}

// ---------------- fp32 -> bf16 bulk convert ----------------
__global__ void cvt_f32_bf16(const float* __restrict__ s, u16* __restrict__ d, int n8) {
  int i = blockIdx.x * blockDim.x + threadIdx.x;
  int stride = gridDim.x * blockDim.x;
  for (; i < n8; i += stride) {
    const float4* s4 = (const float4*)s + (size_t)i * 2;
    float4 x0 = s4[0], x1 = s4[1];
    u16x8 o;
    o[0] = f2bf(x0.x); o[1] = f2bf(x0.y); o[2] = f2bf(x0.z); o[3] = f2bf(x0.w);
    o[4] = f2bf(x1.x); o[5] = f2bf(x1.y); o[6] = f2bf(x1.z); o[7] = f2bf(x1.w);
    *((u16x8*)d + i) = o;
  }
}

// ---------------- router ----------------
DEVFN void top2(const float* __restrict__ logits, int t, int& i0, int& i1, float& v0, float& v1) {
  float l[E];
#pragma unroll
  for (int i = 0; i < E; i++) l[i] = logits[t * E + i];
  i0 = 0; v0 = l[0];
#pragma unroll
  for (int i = 1; i < E; i++) if (l[i] > v0) { v0 = l[i]; i0 = i; }
  i1 = -1; v1 = -1e30f;
#pragma unroll
  for (int i = 0; i < E; i++) if (i != i0 && l[i] > v1) { v1 = l[i]; i1 = i; }
}

__global__ void router_count(const float* __restrict__ logits, int* __restrict__ counts) {
  int t = blockIdx.x * blockDim.x + threadIdx.x;
  if (t >= T) return;
  int i0, i1; float v0, v1;
  top2(logits, t, i0, i1, v0, v1);
  atomicAdd(&counts[i0], 1);
  atomicAdd(&counts[i1], 1);
}

__global__ void build_tiles(const int* __restrict__ counts, int* __restrict__ offsets,
                            int* __restrict__ ntiles, int* __restrict__ tile_e,
                            int* __restrict__ tile_r0) {
  if (threadIdx.x != 0 || blockIdx.x != 0) return;
  int s = 0, nt = 0;
  for (int e = 0; e < E; e++) {
    offsets[e] = s;
    for (int r = 0; r < counts[e]; r += BM) { tile_e[nt] = e; tile_r0[nt] = r; nt++; }
    s += counts[e];
  }
  offsets[E] = s;
  ntiles[0] = nt;
}

__global__ void router_scatter(const float* __restrict__ logits, const int* __restrict__ offsets,
                               int* __restrict__ cursor, int* __restrict__ slot_tok,
                               float* __restrict__ slot_w, int* __restrict__ pos) {
  int t = blockIdx.x * blockDim.x + threadIdx.x;
  if (t >= T) return;
  int i0, i1; float v0, v1;
  top2(logits, t, i0, i1, v0, v1);
  float ee = __expf(v1 - v0);
  float w0 = 1.f / (1.f + ee);
  float w1 = 1.f - w0;
  int p0 = offsets[i0] + atomicAdd(&cursor[i0], 1);
  slot_tok[p0] = t; slot_w[p0] = w0; pos[2 * t] = p0;
  int p1 = offsets[i1] + atomicAdd(&cursor[i1], 1);
  slot_tok[p1] = t; slot_w[p1] = w1; pos[2 * t + 1] = p1;
}

// ---------------- GEMM1: h = silu(x@w1^T) * (x@w3^T) ----------------
// block 128 rows x 128 cols of BOTH gate and up; 4 waves (2x2), wave = 64x64 each.
// LDS tiles [128][64] bf16, XOR-swizzled: LDS chunk c holds global chunk (c&7)^((c>>3)&7).
__global__ __launch_bounds__(256, 2) void gemm1(
    const u16* __restrict__ xb, const u16* __restrict__ w13b,
    const int* __restrict__ offsets, const int* __restrict__ ntiles,
    const int* __restrict__ tile_e, const int* __restrict__ tile_r0,
    const int* __restrict__ slot_tok, u16* __restrict__ hb) {
  int ti = blockIdx.x;
  if (ti >= ntiles[0]) return;
  int e = tile_e[ti], row0 = tile_r0[ti];
  int n0 = offsets[e], ne = offsets[e + 1] - n0;
  int j0 = blockIdx.y * 128;

  __shared__ u16 As[BM * BK];
  __shared__ u16 Bgs[BM * BK];
  __shared__ u16 Bus[BM * BK];

  int tid = threadIdx.x, w = tid >> 6, l = tid & 63;
  int lr = l & 15, lh = l >> 4;
  int wm = w >> 1, wn = w & 1;

  const char* xc = (const char*)xb;
  const char* wc = (const char*)w13b;

  size_t aoff[4], goff[4], uoff[4];
#pragma unroll
  for (int i = 0; i < 4; i++) {
    int c = tid + i * 256;
    int r = c >> 3;                      // row within 128
    int gch = (c & 7) ^ (r & 7);         // inverse-swizzled global chunk
    int rr = row0 + r; if (rr > ne - 1) rr = ne - 1;
    aoff[i] = (size_t)slot_tok[n0 + rr] * (H * 2) + (size_t)(gch * 16);
    goff[i] = ((size_t)e * (2 * I) + (j0 + r)) * (H * 2) + (size_t)(gch * 16);
    uoff[i] = goff[i] + (size_t)I * (H * 2);
  }

  f32x4 accg[4][4] = {};
  f32x4 accu[4][4] = {};

  char* AsB = (char*)As; char* BgB = (char*)Bgs; char* BuB = (char*)Bus;

  for (int k0 = 0; k0 < H; k0 += BK) {
    __syncthreads();
    size_t kb = (size_t)(k0 * 2);
#pragma unroll
    for (int i = 0; i < 4; i++) {
      int d = (tid + i * 256) * 16;      // linear LDS dest (wave base + lane*16)
      glds16(xc + aoff[i] + kb, AsB + d);
      glds16(wc + goff[i] + kb, BgB + d);
      glds16(wc + uoff[i] + kb, BuB + d);
    }
    __syncthreads();

#pragma unroll
    for (int ks = 0; ks < 2; ks++) {
      bf16x8 a[4];
#pragma unroll
      for (int mi = 0; mi < 4; mi++) {
        int row = wm * 64 + mi * 16 + lr;
        a[mi] = *(const bf16x8*)(AsB + row * BKB + (((ks * 4 + lh) ^ (row & 7)) * 16));
      }
#pragma unroll
      for (int ni = 0; ni < 4; ni++) {
        int row = wn * 64 + ni * 16 + lr;
        int boff = row * BKB + (((ks * 4 + lh) ^ (row & 7)) * 16);
        bf16x8 bg = *(const bf16x8*)(BgB + boff);
#pragma unroll
        for (int mi = 0; mi < 4; mi++)
          accg[mi][ni] = __builtin_amdgcn_mfma_f32_16x16x32_bf16(a[mi], bg, accg[mi][ni], 0, 0, 0);
        bf16x8 bu = *(const bf16x8*)(BuB + boff);
#pragma unroll
        for (int mi = 0; mi < 4; mi++)
          accu[mi][ni] = __builtin_amdgcn_mfma_f32_16x16x32_bf16(a[mi], bu, accu[mi][ni], 0, 0, 0);
      }
    }
  }

#pragma unroll
  for (int mi = 0; mi < 4; mi++) {
    int Rb = row0 + wm * 64 + mi * 16 + lh * 4;
#pragma unroll
    for (int ni = 0; ni < 4; ni++) {
      int col = j0 + wn * 64 + ni * 16 + lr;
      f32x4 g = accg[mi][ni], u = accu[mi][ni];
#pragma unroll
      for (int r = 0; r < 4; r++) {
        int R = Rb + r;
        if (R < ne) {
          float gg = g[r];
          float hh = (gg / (1.f + __expf(-gg))) * u[r];
          hb[(size_t)(n0 + R) * I + col] = f2bf(hh);
        }
      }
    }
  }
}

// ---------------- GEMM2: ys[slot] = slot_w * (h@w2^T) ----------------
__global__ __launch_bounds__(256, 2) void gemm2(
    const u16* __restrict__ hb, const u16* __restrict__ w2b,
    const int* __restrict__ offsets, const int* __restrict__ ntiles,
    const int* __restrict__ tile_e, const int* __restrict__ tile_r0,
    const float* __restrict__ slot_w, float* __restrict__ ys) {
  int ti = blockIdx.x;
  if (ti >= ntiles[0]) return;
  int e = tile_e[ti], row0 = tile_r0[ti];
  int n0 = offsets[e], ne = offsets[e + 1] - n0;
  int j0 = blockIdx.y * 128;

  __shared__ u16 As[BM * BK];
  __shared__ u16 Bs[BM * BK];

  int tid = threadIdx.x, w = tid >> 6, l = tid & 63;
  int lr = l & 15, lh = l >> 4;
  int wm = w >> 1, wn = w & 1;

  const char* hc = (const char*)hb;
  const char* wc = (const char*)w2b;

  size_t aoff[4], boff[4];
#pragma unroll
  for (int i = 0; i < 4; i++) {
    int c = tid + i * 256;
    int r = c >> 3;
    int gch = (c & 7) ^ (r & 7);
    int rr = row0 + r; if (rr > ne - 1) rr = ne - 1;
    aoff[i] = (size_t)(n0 + rr) * (I * 2) + (size_t)(gch * 16);
    boff[i] = ((size_t)e * H + (j0 + r)) * (I * 2) + (size_t)(gch * 16);
  }

  f32x4 acc[4][4] = {};
  char* AsB = (char*)As; char* BsB = (char*)Bs;

  for (int k0 = 0; k0 < I; k0 += BK) {
    __syncthreads();
    size_t kb = (size_t)(k0 * 2);
#pragma unroll
    for (int i = 0; i < 4; i++) {
      int d = (tid + i * 256) * 16;
      glds16(hc + aoff[i] + kb, AsB + d);
      glds16(wc + boff[i] + kb, BsB + d);
    }
    __syncthreads();

#pragma unroll
    for (int ks = 0; ks < 2; ks++) {
      bf16x8 a[4];
#pragma unroll
      for (int mi = 0; mi < 4; mi++) {
        int row = wm * 64 + mi * 16 + lr;
        a[mi] = *(const bf16x8*)(AsB + row * BKB + (((ks * 4 + lh) ^ (row & 7)) * 16));
      }
#pragma unroll
      for (int nj = 0; nj < 4; nj++) {
        int row = wn * 64 + nj * 16 + lr;
        bf16x8 b = *(const bf16x8*)(BsB + row * BKB + (((ks * 4 + lh) ^ (row & 7)) * 16));
#pragma unroll
        for (int mi = 0; mi < 4; mi++)
          acc[mi][nj] = __builtin_amdgcn_mfma_f32_16x16x32_bf16(a[mi], b, acc[mi][nj], 0, 0, 0);
      }
    }
  }

#pragma unroll
  for (int mi = 0; mi < 4; mi++) {
    int Rb = row0 + wm * 64 + mi * 16 + lh * 4;
#pragma unroll
    for (int r = 0; r < 4; r++) {
      int R = Rb + r;
      if (R < ne) {
        float cw = slot_w[n0 + R];
        float* yrow = ys + (size_t)(n0 + R) * H + j0 + wn * 64 + lr;
#pragma unroll
        for (int nj = 0; nj < 4; nj++)
          yrow[nj * 16] = acc[mi][nj][r] * cw;
      }
    }
  }
}

// ---------------- combine: out[t] = ys[p0[t]] + ys[p1[t]] ----------------
__global__ void combine(const float* __restrict__ ys, const int* __restrict__ pos,
                        float* __restrict__ out) {
  int idx = blockIdx.x * blockDim.x + threadIdx.x;   // one float4 per thread
  int t = idx >> 8;                                   // H/4 = 256 float4 per token
  int j = idx & 255;
  int p0 = pos[2 * t], p1 = pos[2 * t + 1];
  const float4* y4 = (const float4*)ys;
  float4 a = y4[(size_t)p0 * 256 + j];
  float4 b = y4[(size_t)p1 * 256 + j];
  float4 o; o.x = a.x + b.x; o.y = a.y + b.y; o.z = a.z + b.z; o.w = a.w + b.w;
  ((float4*)out)[idx] = o;
}

// ---------------- host ----------------
extern "C" void kernel_launch(void* const* d_in, const int* in_sizes, int n_in,
                              void* d_out, int out_size, void* d_ws, size_t ws_size,
                              hipStream_t stream) {
  const float* x      = (const float*)d_in[0];
  const float* logits = (const float*)d_in[1];
  const float* w13    = (const float*)d_in[2];
  const float* w2     = (const float*)d_in[3];
  float* out = (float*)d_out;

  char* ws = (char*)d_ws;
  size_t off = 0;
  auto alloc = [&](size_t b) { size_t p = off; off += (b + 255) & ~(size_t)255; return p; };
  int*   counts   = (int*)(ws + alloc(E * 4));
  int*   cursor   = (int*)(ws + alloc(E * 4));
  int*   offsets  = (int*)(ws + alloc((E + 1) * 4));
  int*   ntiles   = (int*)(ws + alloc(4));
  int*   tile_e   = (int*)(ws + alloc(MAX_TILES * 4));
  int*   tile_r0  = (int*)(ws + alloc(MAX_TILES * 4));
  int*   slot_tok = (int*)(ws + alloc(NSLOT * 4));
  float* slot_w   = (float*)(ws + alloc(NSLOT * 4));
  int*   pos      = (int*)(ws + alloc(2 * T * 4));
  u16*   xb       = (u16*)(ws + alloc((size_t)T * H * 2));
  size_t w13b_off = alloc((size_t)E * 2 * I * H * 2);
  u16*   w13b     = (u16*)(ws + w13b_off);
  u16*   w2b      = (u16*)(ws + alloc((size_t)E * H * I * 2));
  u16*   hb       = (u16*)(ws + alloc((size_t)NSLOT * I * 2));
  // ys (NSLOT*H fp32 = 33.5 MB) aliases w13b (67 MB, dead after gemm1)
  float* ys       = (float*)(ws + w13b_off);
  if (ws_size < off) return;

  hipMemsetAsync(ws, 0, 512, stream);   // counts + cursor

  cvt_f32_bf16<<<2048, 256, 0, stream>>>(x, xb, T * H / 8);
  cvt_f32_bf16<<<2048, 256, 0, stream>>>(w13, w13b, E * 2 * I * H / 8);
  cvt_f32_bf16<<<2048, 256, 0, stream>>>(w2, w2b, E * H * I / 8);

  router_count<<<T / 256, 256, 0, stream>>>(logits, counts);
  build_tiles<<<1, 64, 0, stream>>>(counts, offsets, ntiles, tile_e, tile_r0);
  router_scatter<<<T / 256, 256, 0, stream>>>(logits, offsets, cursor, slot_tok, slot_w, pos);

  gemm1<<<dim3(MAX_TILES, I / 128, 1), 256, 0, stream>>>(
      xb, w13b, offsets, ntiles, tile_e, tile_r0, slot_tok, hb);
  gemm2<<<dim3(MAX_TILES, H / 128, 1), 256, 0, stream>>>(
      hb, w2b, offsets, ntiles, tile_e, tile_r0, slot_w, ys);
  combine<<<T * H / 4 / 256, 256, 0, stream>>>(ys, pos, out);
}

// Round 8
// 500.320 us; speedup vs baseline: 1.0978x; 1.0155x over previous
//
#include <hip/hip_runtime.h>

typedef __bf16 bf16x8 __attribute__((ext_vector_type(8)));
typedef float f32x4 __attribute__((ext_vector_type(4)));
typedef unsigned short u16;
typedef unsigned int u32;
typedef u16 u16x8 __attribute__((ext_vector_type(8)));

#define DEVFN static __device__ __forceinline__

constexpr int T = 4096, H = 1024, I = 2048, E = 8;
constexpr int NSLOT = T * 2;
constexpr int MAX_TILES = 72;

DEVFN u16 f2bf(float f) {
  u32 u = __builtin_bit_cast(u32, f);
  u32 r = (u + 0x7FFFu + ((u >> 16) & 1u)) >> 16;  // RNE
  return (u16)r;
}

DEVFN void glds16(const void* g, void* l) {
  __builtin_amdgcn_global_load_lds(
      (const __attribute__((address_space(1))) void*)g,
      (__attribute__((address_space(3))) void*)l, 16, 0, 0);
}

// ---------------- merged fp32 -> bf16 convert ----------------
DEVFN void cvt_region(const float* __restrict__ s, u16* __restrict__ d, int n8,
                      int id0, int stride) {
  for (int i = id0; i < n8; i += stride) {
    const float4* s4 = (const float4*)s + (size_t)i * 2;
    float4 x0 = s4[0], x1 = s4[1];
    u16x8 o;
    o[0] = f2bf(x0.x); o[1] = f2bf(x0.y); o[2] = f2bf(x0.z); o[3] = f2bf(x0.w);
    o[4] = f2bf(x1.x); o[5] = f2bf(x1.y); o[6] = f2bf(x1.z); o[7] = f2bf(x1.w);
    *((u16x8*)d + i) = o;
  }
}

__global__ void cvt_all(const float* __restrict__ x, const float* __restrict__ w13,
                        const float* __restrict__ w2, u16* __restrict__ xb,
                        u16* __restrict__ w13b, u16* __restrict__ w2b) {
  int id0 = blockIdx.x * blockDim.x + threadIdx.x;
  int stride = gridDim.x * blockDim.x;
  cvt_region(x,   xb,   T * H / 8,         id0, stride);
  cvt_region(w13, w13b, E * 2 * I * H / 8, id0, stride);
  cvt_region(w2,  w2b,  E * H * I / 8,     id0, stride);
}

// ---------------- single-block router: top2 + offsets + tiles + scatter ----------------
DEVFN void top2(const float* __restrict__ logits, int t, int& i0, int& i1, float& v0, float& v1) {
  float l[E];
#pragma unroll
  for (int i = 0; i < E; i++) l[i] = logits[t * E + i];
  i0 = 0; v0 = l[0];
#pragma unroll
  for (int i = 1; i < E; i++) if (l[i] > v0) { v0 = l[i]; i0 = i; }
  i1 = -1; v1 = -1e30f;
#pragma unroll
  for (int i = 0; i < E; i++) if (i != i0 && l[i] > v1) { v1 = l[i]; i1 = i; }
}

__global__ void router_all(const float* __restrict__ logits, int* __restrict__ offsets,
                           int* __restrict__ ntiles, int* __restrict__ tile_e,
                           int* __restrict__ tile_r0, int* __restrict__ slot_tok,
                           float* __restrict__ slot_w, int* __restrict__ pos) {
  __shared__ int cnt[E], cur[E], offs[E + 1];
  int tid = threadIdx.x;
  if (tid < E) { cnt[tid] = 0; cur[tid] = 0; }
  __syncthreads();

  constexpr int PT = T / 256;  // 16 tokens per thread
  int e0[PT], e1[PT]; float w0v[PT], w1v[PT];
#pragma unroll
  for (int i = 0; i < PT; i++) {
    int t = tid + i * 256;
    int i0, i1; float v0, v1;
    top2(logits, t, i0, i1, v0, v1);
    float ee = __expf(v1 - v0);
    float w0 = 1.f / (1.f + ee);
    e0[i] = i0; e1[i] = i1; w0v[i] = w0; w1v[i] = 1.f - w0;
    atomicAdd(&cnt[i0], 1);
    atomicAdd(&cnt[i1], 1);
  }
  __syncthreads();
  if (tid == 0) {
    int s = 0, nt = 0;
    for (int e = 0; e < E; e++) {
      offs[e] = s; offsets[e] = s;
      for (int r = 0; r < cnt[e]; r += 128) { tile_e[nt] = e; tile_r0[nt] = r; nt++; }
      s += cnt[e];
    }
    offs[E] = s; offsets[E] = s;
    ntiles[0] = nt;
  }
  __syncthreads();
#pragma unroll
  for (int i = 0; i < PT; i++) {
    int t = tid + i * 256;
    int p0 = offs[e0[i]] + atomicAdd(&cur[e0[i]], 1);
    slot_tok[p0] = t; slot_w[p0] = w0v[i]; pos[2 * t] = p0;
    int p1 = offs[e1[i]] + atomicAdd(&cur[e1[i]], 1);
    slot_tok[p1] = t; slot_w[p1] = w1v[i]; pos[2 * t + 1] = p1;
  }
}

// ---------------- GEMM1: h = silu(x@w1^T)*(x@w3^T), 2-phase dbuf pipeline ----------------
// 128 rows x (128 gate + 128 up) cols; 4 waves (2x2), wave = 64x64 of both.
// BK=32 (64B rows), double-buffered LDS (3 tiles x 8KB x 2 = 48KB).
// Swizzle: LDS chunk (r, ch) holds global chunk ch ^ ((r>>1)&3)  -> 2 lanes/bank = free.
__global__ __launch_bounds__(256, 2) void gemm1(
    const u16* __restrict__ xb, const u16* __restrict__ w13b,
    const int* __restrict__ offsets, const int* __restrict__ ntiles,
    const int* __restrict__ tile_e, const int* __restrict__ tile_r0,
    const int* __restrict__ slot_tok, u16* __restrict__ hb) {
  int ti = blockIdx.x;
  if (ti >= ntiles[0]) return;
  int e = tile_e[ti], row0 = tile_r0[ti];
  int n0 = offsets[e], ne = offsets[e + 1] - n0;
  int j0 = blockIdx.y * 128;

  constexpr int TB = 128 * 32;           // elems per tile buffer
  __shared__ u16 As[2 * TB];
  __shared__ u16 Bgs[2 * TB];
  __shared__ u16 Bus[2 * TB];

  int tid = threadIdx.x, w = tid >> 6, l = tid & 63;
  int lr = l & 15, lh = l >> 4;          // lh in 0..3 = 16B chunk index (K slice)
  int wm = w >> 1, wn = w & 1;

  const char* xc = (const char*)xb;
  const char* wc = (const char*)w13b;

  // staging: chunk c = tid + i*256; r = c>>2, ch = c&3; global chunk = ch^((r>>1)&3)
  size_t aoff[2], goff[2], uoff[2];
#pragma unroll
  for (int i = 0; i < 2; i++) {
    int c = tid + i * 256;
    int r = c >> 2;
    int gch = (c & 3) ^ ((r >> 1) & 3);
    int rr = row0 + r; if (rr > ne - 1) rr = ne - 1;
    aoff[i] = (size_t)slot_tok[n0 + rr] * (H * 2) + (size_t)(gch * 16);
    goff[i] = ((size_t)e * (2 * I) + (j0 + r)) * (H * 2) + (size_t)(gch * 16);
    uoff[i] = goff[i] + (size_t)I * (H * 2);
  }

  char* AsB = (char*)As; char* BgB = (char*)Bgs; char* BuB = (char*)Bus;

  auto stage = [&](int buf, int k0) {
    size_t kb = (size_t)(k0 * 2);
    char* Ad = AsB + buf * (TB * 2);
    char* Gd = BgB + buf * (TB * 2);
    char* Ud = BuB + buf * (TB * 2);
#pragma unroll
    for (int i = 0; i < 2; i++) {
      int d = (tid + i * 256) * 16;
      glds16(xc + aoff[i] + kb, Ad + d);
      glds16(wc + goff[i] + kb, Gd + d);
      glds16(wc + uoff[i] + kb, Ud + d);
    }
  };

  f32x4 accg[4][4] = {};
  f32x4 accu[4][4] = {};

  constexpr int NSTEP = H / 32;          // 32
  stage(0, 0);                           // prologue: 6 loads in flight

  for (int t = 0; t < NSTEP; ++t) {
    int cb = t & 1;
    if (t + 1 < NSTEP) {
      stage(cb ^ 1, (t + 1) * 32);                     // 6 more in flight (12 total)
      asm volatile("s_waitcnt vmcnt(6)" ::: "memory"); // current tile's 6 done
    } else {
      asm volatile("s_waitcnt vmcnt(0)" ::: "memory");
    }
    __builtin_amdgcn_s_barrier();        // all waves' current-tile loads landed

    const char* Ab = AsB + cb * (TB * 2);
    const char* Gb = BgB + cb * (TB * 2);
    const char* Ub = BuB + cb * (TB * 2);
    bf16x8 a[4];
#pragma unroll
    for (int mi = 0; mi < 4; mi++) {
      int row = wm * 64 + mi * 16 + lr;
      a[mi] = *(const bf16x8*)(Ab + row * 64 + ((lh ^ ((row >> 1) & 3)) * 16));
    }
#pragma unroll
    for (int ni = 0; ni < 4; ni++) {
      int row = wn * 64 + ni * 16 + lr;
      int boff = row * 64 + ((lh ^ ((row >> 1) & 3)) * 16);
      bf16x8 bg = *(const bf16x8*)(Gb + boff);
#pragma unroll
      for (int mi = 0; mi < 4; mi++)
        accg[mi][ni] = __builtin_amdgcn_mfma_f32_16x16x32_bf16(a[mi], bg, accg[mi][ni], 0, 0, 0);
      bf16x8 bu = *(const bf16x8*)(Ub + boff);
#pragma unroll
      for (int mi = 0; mi < 4; mi++)
        accu[mi][ni] = __builtin_amdgcn_mfma_f32_16x16x32_bf16(a[mi], bu, accu[mi][ni], 0, 0, 0);
    }
    __builtin_amdgcn_s_barrier();        // everyone done reading cb before overwrite
    __builtin_amdgcn_sched_barrier(0);   // pin: nothing crosses this point
  }

#pragma unroll
  for (int mi = 0; mi < 4; mi++) {
    int Rb = row0 + wm * 64 + mi * 16 + lh * 4;
#pragma unroll
    for (int ni = 0; ni < 4; ni++) {
      int col = j0 + wn * 64 + ni * 16 + lr;
      f32x4 g = accg[mi][ni], u = accu[mi][ni];
#pragma unroll
      for (int r = 0; r < 4; r++) {
        int R = Rb + r;
        if (R < ne) {
          float gg = g[r];
          float hh = (gg / (1.f + __expf(-gg))) * u[r];
          hb[(size_t)(n0 + R) * I + col] = f2bf(hh);
        }
      }
    }
  }
}

// ---------------- GEMM2: ys[slot] = slot_w*(h@w2^T), same 2-phase dbuf pipeline ----------------
// 128x128 tile, BK=32, 2 tiles x 2 bufs x 8KB = 32KB LDS. 3 blocks/CU target.
__global__ __launch_bounds__(256, 3) void gemm2(
    const u16* __restrict__ hb, const u16* __restrict__ w2b,
    const int* __restrict__ offsets, const int* __restrict__ ntiles,
    const int* __restrict__ tile_e, const int* __restrict__ tile_r0,
    const float* __restrict__ slot_w, float* __restrict__ ys) {
  int ti = blockIdx.x;
  if (ti >= ntiles[0]) return;
  int e = tile_e[ti], row0 = tile_r0[ti];
  int n0 = offsets[e], ne = offsets[e + 1] - n0;
  int j0 = blockIdx.y * 128;

  constexpr int TB = 128 * 32;
  __shared__ u16 As[2 * TB];
  __shared__ u16 Bs[2 * TB];

  int tid = threadIdx.x, w = tid >> 6, l = tid & 63;
  int lr = l & 15, lh = l >> 4;
  int wm = w >> 1, wn = w & 1;

  const char* hc = (const char*)hb;
  const char* wc = (const char*)w2b;

  size_t aoff[2], boff[2];
#pragma unroll
  for (int i = 0; i < 2; i++) {
    int c = tid + i * 256;
    int r = c >> 2;
    int gch = (c & 3) ^ ((r >> 1) & 3);
    int rr = row0 + r; if (rr > ne - 1) rr = ne - 1;
    aoff[i] = (size_t)(n0 + rr) * (I * 2) + (size_t)(gch * 16);
    boff[i] = ((size_t)e * H + (j0 + r)) * (I * 2) + (size_t)(gch * 16);
  }

  char* AsB = (char*)As; char* BsB = (char*)Bs;

  auto stage = [&](int buf, int k0) {
    size_t kb = (size_t)(k0 * 2);
    char* Ad = AsB + buf * (TB * 2);
    char* Bd = BsB + buf * (TB * 2);
#pragma unroll
    for (int i = 0; i < 2; i++) {
      int d = (tid + i * 256) * 16;
      glds16(hc + aoff[i] + kb, Ad + d);
      glds16(wc + boff[i] + kb, Bd + d);
    }
  };

  f32x4 acc[4][4] = {};

  constexpr int NSTEP = I / 32;          // 64
  stage(0, 0);                           // prologue: 4 loads in flight

  for (int t = 0; t < NSTEP; ++t) {
    int cb = t & 1;
    if (t + 1 < NSTEP) {
      stage(cb ^ 1, (t + 1) * 32);                     // 4 more (8 total)
      asm volatile("s_waitcnt vmcnt(4)" ::: "memory"); // current tile's 4 done
    } else {
      asm volatile("s_waitcnt vmcnt(0)" ::: "memory");
    }
    __builtin_amdgcn_s_barrier();

    const char* Ab = AsB + cb * (TB * 2);
    const char* Bb = BsB + cb * (TB * 2);
    bf16x8 a[4];
#pragma unroll
    for (int mi = 0; mi < 4; mi++) {
      int row = wm * 64 + mi * 16 + lr;
      a[mi] = *(const bf16x8*)(Ab + row * 64 + ((lh ^ ((row >> 1) & 3)) * 16));
    }
#pragma unroll
    for (int nj = 0; nj < 4; nj++) {
      int row = wn * 64 + nj * 16 + lr;
      bf16x8 b = *(const bf16x8*)(Bb + row * 64 + ((lh ^ ((row >> 1) & 3)) * 16));
#pragma unroll
      for (int mi = 0; mi < 4; mi++)
        acc[mi][nj] = __builtin_amdgcn_mfma_f32_16x16x32_bf16(a[mi], b, acc[mi][nj], 0, 0, 0);
    }
    __builtin_amdgcn_s_barrier();
    __builtin_amdgcn_sched_barrier(0);
  }

#pragma unroll
  for (int mi = 0; mi < 4; mi++) {
    int Rb = row0 + wm * 64 + mi * 16 + lh * 4;
#pragma unroll
    for (int r = 0; r < 4; r++) {
      int R = Rb + r;
      if (R < ne) {
        float cw = slot_w[n0 + R];
        float* yrow = ys + (size_t)(n0 + R) * H + j0 + wn * 64 + lr;
#pragma unroll
        for (int nj = 0; nj < 4; nj++)
          yrow[nj * 16] = acc[mi][nj][r] * cw;
      }
    }
  }
}

// ---------------- combine: out[t] = ys[p0[t]] + ys[p1[t]] ----------------
__global__ void combine(const float* __restrict__ ys, const int* __restrict__ pos,
                        float* __restrict__ out) {
  int idx = blockIdx.x * blockDim.x + threadIdx.x;
  int t = idx >> 8;
  int j = idx & 255;
  int p0 = pos[2 * t], p1 = pos[2 * t + 1];
  const float4* y4 = (const float4*)ys;
  float4 a = y4[(size_t)p0 * 256 + j];
  float4 b = y4[(size_t)p1 * 256 + j];
  float4 o; o.x = a.x + b.x; o.y = a.y + b.y; o.z = a.z + b.z; o.w = a.w + b.w;
  ((float4*)out)[idx] = o;
}

// ---------------- host ----------------
extern "C" void kernel_launch(void* const* d_in, const int* in_sizes, int n_in,
                              void* d_out, int out_size, void* d_ws, size_t ws_size,
                              hipStream_t stream) {
  const float* x      = (const float*)d_in[0];
  const float* logits = (const float*)d_in[1];
  const float* w13    = (const float*)d_in[2];
  const float* w2     = (const float*)d_in[3];
  float* out = (float*)d_out;

  char* ws = (char*)d_ws;
  size_t off = 0;
  auto alloc = [&](size_t b) { size_t p = off; off += (b + 255) & ~(size_t)255; return p; };
  int*   offsets  = (int*)(ws + alloc((E + 1) * 4));
  int*   ntiles   = (int*)(ws + alloc(4));
  int*   tile_e   = (int*)(ws + alloc(MAX_TILES * 4));
  int*   tile_r0  = (int*)(ws + alloc(MAX_TILES * 4));
  int*   slot_tok = (int*)(ws + alloc(NSLOT * 4));
  float* slot_w   = (float*)(ws + alloc(NSLOT * 4));
  int*   pos      = (int*)(ws + alloc(2 * T * 4));
  u16*   xb       = (u16*)(ws + alloc((size_t)T * H * 2));
  size_t w13b_off = alloc((size_t)E * 2 * I * H * 2);
  u16*   w13b     = (u16*)(ws + w13b_off);
  u16*   w2b      = (u16*)(ws + alloc((size_t)E * H * I * 2));
  u16*   hb       = (u16*)(ws + alloc((size_t)NSLOT * I * 2));
  float* ys       = (float*)(ws + w13b_off);  // aliases w13b (dead after gemm1)
  if (ws_size < off) return;

  cvt_all<<<2048, 256, 0, stream>>>(x, w13, w2, xb, w13b, w2b);
  router_all<<<1, 256, 0, stream>>>(logits, offsets, ntiles, tile_e, tile_r0,
                                    slot_tok, slot_w, pos);
  gemm1<<<dim3(MAX_TILES, I / 128, 1), 256, 0, stream>>>(
      xb, w13b, offsets, ntiles, tile_e, tile_r0, slot_tok, hb);
  gemm2<<<dim3(MAX_TILES, H / 128, 1), 256, 0, stream>>>(
      hb, w2b, offsets, ntiles, tile_e, tile_r0, slot_w, ys);
  combine<<<T * H / 4 / 256, 256, 0, stream>>>(ys, pos, out);
}

// Round 10
// 431.843 us; speedup vs baseline: 1.2719x; 1.1586x over previous
//
#include <hip/hip_runtime.h>

typedef __bf16 bf16x8 __attribute__((ext_vector_type(8)));
typedef float f32x4 __attribute__((ext_vector_type(4)));
typedef unsigned short u16;
typedef unsigned int u32;
typedef u16 u16x8 __attribute__((ext_vector_type(8)));

#define DEVFN static __device__ __forceinline__

constexpr int T = 4096, H = 1024, I = 2048, E = 8;
constexpr int NSLOT = T * 2;
constexpr int BM = 128, BK = 64;     // K elems per step; row = 128 B (full cache line)
constexpr int BKB = BK * 2;
constexpr int MAX_TILES = 72;        // 9 tiles x 8 XCDs

DEVFN u16 f2bf(float f) {
  u32 u = __builtin_bit_cast(u32, f);
  u32 r = (u + 0x7FFFu + ((u >> 16) & 1u)) >> 16;  // RNE
  return (u16)r;
}

DEVFN void glds16(const void* g, void* l) {
  __builtin_amdgcn_global_load_lds(
      (const __attribute__((address_space(1))) void*)g,
      (__attribute__((address_space(3))) void*)l, 16, 0, 0);
}

// ---------------- merged fp32->bf16 convert + router (block 2048) ----------------
DEVFN void cvt_region(const float* __restrict__ s, u16* __restrict__ d, int n8,
                      int id0, int stride) {
  for (int i = id0; i < n8; i += stride) {
    const float4* s4 = (const float4*)s + (size_t)i * 2;
    float4 x0 = s4[0], x1 = s4[1];
    u16x8 o;
    o[0] = f2bf(x0.x); o[1] = f2bf(x0.y); o[2] = f2bf(x0.z); o[3] = f2bf(x0.w);
    o[4] = f2bf(x1.x); o[5] = f2bf(x1.y); o[6] = f2bf(x1.z); o[7] = f2bf(x1.w);
    *((u16x8*)d + i) = o;
  }
}

DEVFN void top2(const float* __restrict__ logits, int t, int& i0, int& i1, float& v0, float& v1) {
  float l[E];
#pragma unroll
  for (int i = 0; i < E; i++) l[i] = logits[t * E + i];
  i0 = 0; v0 = l[0];
#pragma unroll
  for (int i = 1; i < E; i++) if (l[i] > v0) { v0 = l[i]; i0 = i; }
  i1 = -1; v1 = -1e30f;
#pragma unroll
  for (int i = 0; i < E; i++) if (i != i0 && l[i] > v1) { v1 = l[i]; i1 = i; }
}

__global__ void cvt_router(const float* __restrict__ x, const float* __restrict__ w13,
                           const float* __restrict__ w2, const float* __restrict__ logits,
                           u16* __restrict__ xb, u16* __restrict__ w13b, u16* __restrict__ w2b,
                           int* __restrict__ offsets, int* __restrict__ ntiles,
                           int* __restrict__ tile_e, int* __restrict__ tile_r0,
                           int* __restrict__ slot_tok, float* __restrict__ slot_w,
                           int* __restrict__ pos) {
  if (blockIdx.x == 2048) {
    // -------- router: single block --------
    __shared__ int cnt[E], cur[E], offs[E + 1];
    int tid = threadIdx.x;
    if (tid < E) { cnt[tid] = 0; cur[tid] = 0; }
    __syncthreads();
    constexpr int PT = T / 256;
    int e0[PT], e1[PT]; float w0v[PT], w1v[PT];
#pragma unroll
    for (int i = 0; i < PT; i++) {
      int t = tid + i * 256;
      int i0, i1; float v0, v1;
      top2(logits, t, i0, i1, v0, v1);
      float ee = __expf(v1 - v0);
      float w0 = 1.f / (1.f + ee);
      e0[i] = i0; e1[i] = i1; w0v[i] = w0; w1v[i] = 1.f - w0;
      atomicAdd(&cnt[i0], 1);
      atomicAdd(&cnt[i1], 1);
    }
    __syncthreads();
    if (tid == 0) {
      int s = 0, nt = 0;
      for (int e = 0; e < E; e++) {
        offs[e] = s; offsets[e] = s;
        for (int r = 0; r < cnt[e]; r += BM) { tile_e[nt] = e; tile_r0[nt] = r; nt++; }
        s += cnt[e];
      }
      offs[E] = s; offsets[E] = s;
      ntiles[0] = nt;
    }
    __syncthreads();
#pragma unroll
    for (int i = 0; i < PT; i++) {
      int t = tid + i * 256;
      int p0 = offs[e0[i]] + atomicAdd(&cur[e0[i]], 1);
      slot_tok[p0] = t; slot_w[p0] = w0v[i]; pos[2 * t] = p0;
      int p1 = offs[e1[i]] + atomicAdd(&cur[e1[i]], 1);
      slot_tok[p1] = t; slot_w[p1] = w1v[i]; pos[2 * t + 1] = p1;
    }
    return;
  }
  // -------- cvt: blocks 0..2047 --------
  int id0 = blockIdx.x * blockDim.x + threadIdx.x;
  int stride = 2048 * 256;
  cvt_region(x,   xb,   T * H / 8,         id0, stride);
  cvt_region(w13, w13b, E * 2 * I * H / 8, id0, stride);
  cvt_region(w2,  w2b,  E * H * I / 8,     id0, stride);
}

// ---------------- GEMM1: h = silu(x@w1^T)*(x@w3^T)  [round-2 measured structure] ----------------
// 128 rows x (128 gate + 128 up) cols; 4 waves (2x2), wave = 64x64 of both.
// BK=64 (128B rows), single-buffer drain. Swizzle: LDS chunk c holds global chunk (c&7)^(r&7).
// XCD remap: f = blockIdx.x; xcd=f&7, i=f>>3; ti=xcd*9+i%9 (tiles fastest), j0=(i/9)*128.
__global__ __launch_bounds__(256, 2) void gemm1(
    const u16* __restrict__ xb, const u16* __restrict__ w13b,
    const int* __restrict__ offsets, const int* __restrict__ ntiles,
    const int* __restrict__ tile_e, const int* __restrict__ tile_r0,
    const int* __restrict__ slot_tok, u16* __restrict__ hb) {
  int f = blockIdx.x;
  int xcd = f & 7, idx = f >> 3;       // idx in 0..143
  int ti = xcd * 9 + (idx % 9);        // 0..71
  int j0 = (idx / 9) * 128;            // 16 j-blocks
  if (ti >= ntiles[0]) return;
  int e = tile_e[ti], row0 = tile_r0[ti];
  int n0 = offsets[e], ne = offsets[e + 1] - n0;

  __shared__ u16 As[BM * BK];
  __shared__ u16 Bgs[BM * BK];
  __shared__ u16 Bus[BM * BK];

  int tid = threadIdx.x, w = tid >> 6, l = tid & 63;
  int lr = l & 15, lh = l >> 4;
  int wm = w >> 1, wn = w & 1;

  const char* xc = (const char*)xb;
  const char* wc = (const char*)w13b;

  size_t aoff[4], goff[4], uoff[4];
#pragma unroll
  for (int i = 0; i < 4; i++) {
    int c = tid + i * 256;
    int r = c >> 3;                      // row within 128
    int gch = (c & 7) ^ (r & 7);         // inverse-swizzled global chunk
    int rr = row0 + r; if (rr > ne - 1) rr = ne - 1;
    aoff[i] = (size_t)slot_tok[n0 + rr] * (H * 2) + (size_t)(gch * 16);
    goff[i] = ((size_t)e * (2 * I) + (j0 + r)) * (H * 2) + (size_t)(gch * 16);
    uoff[i] = goff[i] + (size_t)I * (H * 2);
  }

  f32x4 accg[4][4] = {};
  f32x4 accu[4][4] = {};

  char* AsB = (char*)As; char* BgB = (char*)Bgs; char* BuB = (char*)Bus;

  for (int k0 = 0; k0 < H; k0 += BK) {
    __syncthreads();
    size_t kb = (size_t)(k0 * 2);
#pragma unroll
    for (int i = 0; i < 4; i++) {
      int d = (tid + i * 256) * 16;      // linear LDS dest
      glds16(xc + aoff[i] + kb, AsB + d);
      glds16(wc + goff[i] + kb, BgB + d);
      glds16(wc + uoff[i] + kb, BuB + d);
    }
    __syncthreads();

#pragma unroll
    for (int ks = 0; ks < 2; ks++) {
      bf16x8 a[4];
#pragma unroll
      for (int mi = 0; mi < 4; mi++) {
        int row = wm * 64 + mi * 16 + lr;
        a[mi] = *(const bf16x8*)(AsB + row * BKB + (((ks * 4 + lh) ^ (row & 7)) * 16));
      }
#pragma unroll
      for (int ni = 0; ni < 4; ni++) {
        int row = wn * 64 + ni * 16 + lr;
        int boff = row * BKB + (((ks * 4 + lh) ^ (row & 7)) * 16);
        bf16x8 bg = *(const bf16x8*)(BgB + boff);
#pragma unroll
        for (int mi = 0; mi < 4; mi++)
          accg[mi][ni] = __builtin_amdgcn_mfma_f32_16x16x32_bf16(a[mi], bg, accg[mi][ni], 0, 0, 0);
        bf16x8 bu = *(const bf16x8*)(BuB + boff);
#pragma unroll
        for (int mi = 0; mi < 4; mi++)
          accu[mi][ni] = __builtin_amdgcn_mfma_f32_16x16x32_bf16(a[mi], bu, accu[mi][ni], 0, 0, 0);
      }
    }
  }

#pragma unroll
  for (int mi = 0; mi < 4; mi++) {
    int Rb = row0 + wm * 64 + mi * 16 + lh * 4;
#pragma unroll
    for (int ni = 0; ni < 4; ni++) {
      int col = j0 + wn * 64 + ni * 16 + lr;
      f32x4 g = accg[mi][ni], u = accu[mi][ni];
#pragma unroll
      for (int r = 0; r < 4; r++) {
        int R = Rb + r;
        if (R < ne) {
          float gg = g[r];
          float hh = (gg / (1.f + __expf(-gg))) * u[r];
          hb[(size_t)(n0 + R) * I + col] = f2bf(hh);
        }
      }
    }
  }
}

// ---------------- GEMM2: ys[slot] = slot_w*(h@w2^T)  [round-2 measured structure] ----------------
// 128x128, BK=64, single-buffer drain, same swizzle. XCD remap (8 j-blocks).
__global__ __launch_bounds__(256, 2) void gemm2(
    const u16* __restrict__ hb, const u16* __restrict__ w2b,
    const int* __restrict__ offsets, const int* __restrict__ ntiles,
    const int* __restrict__ tile_e, const int* __restrict__ tile_r0,
    const float* __restrict__ slot_w, float* __restrict__ ys) {
  int f = blockIdx.x;
  int xcd = f & 7, idx = f >> 3;       // idx in 0..71
  int ti = xcd * 9 + (idx % 9);        // 0..71
  int j0 = (idx / 9) * 128;            // 8 j-blocks
  if (ti >= ntiles[0]) return;
  int e = tile_e[ti], row0 = tile_r0[ti];
  int n0 = offsets[e], ne = offsets[e + 1] - n0;

  __shared__ u16 As[BM * BK];
  __shared__ u16 Bs[BM * BK];

  int tid = threadIdx.x, w = tid >> 6, l = tid & 63;
  int lr = l & 15, lh = l >> 4;
  int wm = w >> 1, wn = w & 1;

  const char* hc = (const char*)hb;
  const char* wc = (const char*)w2b;

  size_t aoff[4], boff[4];
#pragma unroll
  for (int i = 0; i < 4; i++) {
    int c = tid + i * 256;
    int r = c >> 3;
    int gch = (c & 7) ^ (r & 7);
    int rr = row0 + r; if (rr > ne - 1) rr = ne - 1;
    aoff[i] = (size_t)(n0 + rr) * (I * 2) + (size_t)(gch * 16);
    boff[i] = ((size_t)e * H + (j0 + r)) * (I * 2) + (size_t)(gch * 16);
  }

  f32x4 acc[4][4] = {};
  char* AsB = (char*)As; char* BsB = (char*)Bs;

  for (int k0 = 0; k0 < I; k0 += BK) {
    __syncthreads();
    size_t kb = (size_t)(k0 * 2);
#pragma unroll
    for (int i = 0; i < 4; i++) {
      int d = (tid + i * 256) * 16;
      glds16(hc + aoff[i] + kb, AsB + d);
      glds16(wc + boff[i] + kb, BsB + d);
    }
    __syncthreads();

#pragma unroll
    for (int ks = 0; ks < 2; ks++) {
      bf16x8 a[4];
#pragma unroll
      for (int mi = 0; mi < 4; mi++) {
        int row = wm * 64 + mi * 16 + lr;
        a[mi] = *(const bf16x8*)(AsB + row * BKB + (((ks * 4 + lh) ^ (row & 7)) * 16));
      }
#pragma unroll
      for (int nj = 0; nj < 4; nj++) {
        int row = wn * 64 + nj * 16 + lr;
        bf16x8 b = *(const bf16x8*)(BsB + row * BKB + (((ks * 4 + lh) ^ (row & 7)) * 16));
#pragma unroll
        for (int mi = 0; mi < 4; mi++)
          acc[mi][nj] = __builtin_amdgcn_mfma_f32_16x16x32_bf16(a[mi], b, acc[mi][nj], 0, 0, 0);
      }
    }
  }

#pragma unroll
  for (int mi = 0; mi < 4; mi++) {
    int Rb = row0 + wm * 64 + mi * 16 + lh * 4;
#pragma unroll
    for (int r = 0; r < 4; r++) {
      int R = Rb + r;
      if (R < ne) {
        float cw = slot_w[n0 + R];
        float* yrow = ys + (size_t)(n0 + R) * H + j0 + wn * 64 + lr;
#pragma unroll
        for (int nj = 0; nj < 4; nj++)
          yrow[nj * 16] = acc[mi][nj][r] * cw;
      }
    }
  }
}

// ---------------- combine: out[t] = ys[p0[t]] + ys[p1[t]] ----------------
__global__ void combine(const float* __restrict__ ys, const int* __restrict__ pos,
                        float* __restrict__ out) {
  int idx = blockIdx.x * blockDim.x + threadIdx.x;
  int t = idx >> 8;
  int j = idx & 255;
  int p0 = pos[2 * t], p1 = pos[2 * t + 1];
  const float4* y4 = (const float4*)ys;
  float4 a = y4[(size_t)p0 * 256 + j];
  float4 b = y4[(size_t)p1 * 256 + j];
  float4 o; o.x = a.x + b.x; o.y = a.y + b.y; o.z = a.z + b.z; o.w = a.w + b.w;
  ((float4*)out)[idx] = o;
}

// ---------------- host ----------------
extern "C" void kernel_launch(void* const* d_in, const int* in_sizes, int n_in,
                              void* d_out, int out_size, void* d_ws, size_t ws_size,
                              hipStream_t stream) {
  const float* x      = (const float*)d_in[0];
  const float* logits = (const float*)d_in[1];
  const float* w13    = (const float*)d_in[2];
  const float* w2     = (const float*)d_in[3];
  float* out = (float*)d_out;

  char* ws = (char*)d_ws;
  size_t off = 0;
  auto alloc = [&](size_t b) { size_t p = off; off += (b + 255) & ~(size_t)255; return p; };
  int*   offsets  = (int*)(ws + alloc((E + 1) * 4));
  int*   ntiles   = (int*)(ws + alloc(4));
  int*   tile_e   = (int*)(ws + alloc(MAX_TILES * 4));
  int*   tile_r0  = (int*)(ws + alloc(MAX_TILES * 4));
  int*   slot_tok = (int*)(ws + alloc(NSLOT * 4));
  float* slot_w   = (float*)(ws + alloc(NSLOT * 4));
  int*   pos      = (int*)(ws + alloc(2 * T * 4));
  u16*   xb       = (u16*)(ws + alloc((size_t)T * H * 2));
  size_t w13b_off = alloc((size_t)E * 2 * I * H * 2);
  u16*   w13b     = (u16*)(ws + w13b_off);
  u16*   w2b      = (u16*)(ws + alloc((size_t)E * H * I * 2));
  u16*   hb       = (u16*)(ws + alloc((size_t)NSLOT * I * 2));
  float* ys       = (float*)(ws + w13b_off);  // aliases w13b (dead after gemm1)
  if (ws_size < off) return;

  cvt_router<<<2049, 256, 0, stream>>>(x, w13, w2, logits, xb, w13b, w2b,
                                       offsets, ntiles, tile_e, tile_r0,
                                       slot_tok, slot_w, pos);
  gemm1<<<MAX_TILES * (I / 128), 256, 0, stream>>>(
      xb, w13b, offsets, ntiles, tile_e, tile_r0, slot_tok, hb);
  gemm2<<<MAX_TILES * (H / 128), 256, 0, stream>>>(
      hb, w2b, offsets, ntiles, tile_e, tile_r0, slot_w, ys);
  combine<<<T * H / 4 / 256, 256, 0, stream>>>(ys, pos, out);
}